// Round 2
// baseline (1320.800 us; speedup 1.0000x reference)
//
#include <hip/hip_runtime.h>
#include <hip/hip_bf16.h>

#define NK 1024        // codebook size
#define ND 64          // embedding dim
#define NV 131072      // 32*64*64 input vectors
#define NROWS_BLK 128  // rows per assign block
#define DECAY_F 0.99f
#define OMD_F 0.01f    // fl32(1.0 - 0.99) == fl32(0.01)
#define EPS_F 1e-5f
#define KEPS_F 0.01024f // fl32(1024 * 1e-5)

// ---- ws layout (bytes) ----
// 0    : csq[1024]   f32
// 4096 : ucraw[1024] f32
// 8192 : n_acc f32
// 8196 : usage f32
// 8200 : loss  f64
// 8224 : indices[NV] i32  (512 KB)

// ---------------------------------------------------------------------------
// Kernel 1: codebook_sq with numpy pairwise-8 rounding; zero accumulators.
// ---------------------------------------------------------------------------
__global__ __launch_bounds__(256) void vq_prep(const float* __restrict__ emb,
                                               float* __restrict__ csq,
                                               float* n_acc, float* usage,
                                               double* loss)
{
    int k = blockIdx.x * 256 + threadIdx.x;
    if (k == 0) { *n_acc = 0.f; *usage = 0.f; *loss = 0.0; }
    float p[ND];
    const float4* e4 = reinterpret_cast<const float4*>(emb + (size_t)k * ND);
#pragma unroll
    for (int i = 0; i < 16; ++i) {
        float4 v = e4[i];
        p[4*i+0] = __fmul_rn(v.x, v.x);
        p[4*i+1] = __fmul_rn(v.y, v.y);
        p[4*i+2] = __fmul_rn(v.z, v.z);
        p[4*i+3] = __fmul_rn(v.w, v.w);
    }
    float r[8];
#pragma unroll
    for (int j = 0; j < 8; ++j) r[j] = p[j];
#pragma unroll
    for (int i = 8; i < ND; i += 8)
#pragma unroll
        for (int j = 0; j < 8; ++j) r[j] = __fadd_rn(r[j], p[i+j]);
    csq[k] = __fadd_rn(__fadd_rn(__fadd_rn(r[0], r[1]), __fadd_rn(r[2], r[3])),
                       __fadd_rn(__fadd_rn(r[4], r[5]), __fadd_rn(r[6], r[7])));
}

// ---------------------------------------------------------------------------
// Kernel 2: argmin via wave-uniform (scalar-pipe) embedding reads.
// 256 threads = 128 rows x 2 code-halves. Each thread scans 512 codes with
// e read through uniform indices (-> s_load promotion), x in VGPRs.
// Interleaved encodings zero-fill; LDS combine with first-index tie-break;
// cooperative quantized_flow + loss epilogue.
// ---------------------------------------------------------------------------
__global__ __launch_bounds__(256, 3) void vq_assign(
    const float* __restrict__ x_in, const float* __restrict__ emb,
    const float* __restrict__ csq, float* __restrict__ out_qf,
    float* __restrict__ out_enc, int* __restrict__ indices,
    double* __restrict__ loss_acc)
{
    __shared__ float  sbd[NROWS_BLK][2];
    __shared__ int    sbi[NROWS_BLK][2];
    __shared__ double lds_ls[4];

    const int tid   = threadIdx.x;
    const int lane  = tid & 63;
    const int wv    = tid >> 6;        // 0..3
    const int row_l = tid & 127;       // local row
    const int half  = tid >> 7;        // 0/1, wave-uniform
    const size_t row = (size_t)blockIdx.x * NROWS_BLK + row_l;

    // own input vector -> registers
    float x[ND];
    const float4* xv4 = reinterpret_cast<const float4*>(x_in + row * ND);
#pragma unroll
    for (int i = 0; i < 16; ++i) {
        float4 v = xv4[i];
        x[4*i+0] = v.x; x[4*i+1] = v.y; x[4*i+2] = v.z; x[4*i+3] = v.w;
    }

    // input_sq with numpy pairwise-8 rounding (no FP contraction)
    float isq;
    {
        float r[8];
#pragma unroll
        for (int j = 0; j < 8; ++j) r[j] = __fmul_rn(x[j], x[j]);
#pragma unroll
        for (int i = 8; i < ND; i += 8)
#pragma unroll
            for (int j = 0; j < 8; ++j)
                r[j] = __fadd_rn(r[j], __fmul_rn(x[i+j], x[i+j]));
        isq = __fadd_rn(__fadd_rn(__fadd_rn(r[0], r[1]), __fadd_rn(r[2], r[3])),
                        __fadd_rn(__fadd_rn(r[4], r[5]), __fadd_rn(r[6], r[7])));
    }

    const int kbase = half * 512;
    float best = 3.4e38f;
    int bestk = kbase;

    for (int chunk = 0; chunk < 16; ++chunk) {
#pragma unroll 2
        for (int kk = 0; kk < 32; ++kk) {
            const int k = kbase + chunk * 32 + kk;     // wave-uniform
            const float* er = emb + (size_t)k * ND;    // uniform address
            float dot = 0.f;
#pragma unroll
            for (int d = 0; d < ND; ++d)
                dot = __builtin_fmaf(x[d], er[d], dot);
            float dist = __fsub_rn(__fadd_rn(isq, csq[k]), __fmul_rn(2.0f, dot));
            if (dist < best) { best = dist; bestk = k; }   // first-index ties
        }
        // interleaved encodings zero-fill: wave wv owns rows wv*32..wv*32+31
        {
            int rb = wv * 32 + chunk * 2;
#pragma unroll
            for (int rr = 0; rr < 2; ++rr) {
                size_t zr = (size_t)blockIdx.x * NROWS_BLK + rb + rr;
                float4* dst = reinterpret_cast<float4*>(out_enc + zr * NK);
                float4 z = make_float4(0.f, 0.f, 0.f, 0.f);
#pragma unroll
                for (int j = 0; j < 4; ++j) dst[j * 64 + lane] = z;
            }
        }
    }

    sbd[row_l][half] = best;
    sbi[row_l][half] = bestk;
    __syncthreads();   // drains all zero-stores (vmcnt 0 before s_barrier)

    if (tid < NROWS_BLK) {
        float d0 = sbd[tid][0], d1 = sbd[tid][1];
        int   i0 = sbi[tid][0], i1 = sbi[tid][1];
        int win = (d1 < d0) ? i1 : i0;   // i0 < i1 always -> first-min on tie
        size_t grow = (size_t)blockIdx.x * NROWS_BLK + tid;
        indices[grow] = win;
        out_enc[grow * NK + win] = 1.0f;
        sbi[tid][0] = win;
    }
    __syncthreads();

    // epilogue: wave wv handles rows wv*32..+31, lane = dim
    float lsum = 0.f;
    const int rbase = wv * 32;
    for (int r = 0; r < 32; ++r) {
        int lr = rbase + r;
        int kr = sbi[lr][0];
        size_t grow = (size_t)blockIdx.x * NROWS_BLK + lr;
        float xv = x_in[grow * ND + lane];
        float ev = emb[(size_t)kr * ND + lane];
        out_qf[grow * ND + lane] = __fadd_rn(xv, __fsub_rn(ev, xv));
        float dd = __fsub_rn(xv, ev);
        lsum = __builtin_fmaf(dd, dd, lsum);
    }
    double ls = (double)lsum;
#pragma unroll
    for (int off = 32; off >= 1; off >>= 1) ls += __shfl_xor(ls, off, 64);
    if (lane == 0) lds_ls[wv] = ls;
    __syncthreads();
    if (tid == 0)
        atomicAdd(loss_acc, (lds_ls[0] + lds_ls[1]) + (lds_ls[2] + lds_ls[3]));
}

// ---------------------------------------------------------------------------
// Kernel 3: segment sums — 4 codes per block, scan index array via ballot.
// Wave w covers quarter w of the rows (same order as round 1).
// ---------------------------------------------------------------------------
#define CPB 4
__global__ __launch_bounds__(256) void vq_segsum(
    const float* __restrict__ x_in, const int* __restrict__ indices,
    const float* __restrict__ ema_w, const float* __restrict__ ema_cs,
    float* __restrict__ out_updw, float* __restrict__ ucraw,
    float* __restrict__ n_acc, float* __restrict__ usage)
{
    __shared__ float sacc[4][CPB][64];
    __shared__ int   scnt[4][CPB];
    const int kb   = blockIdx.x * CPB;
    const int tid  = threadIdx.x;
    const int lane = tid & 63;
    const int wv   = tid >> 6;

    float acc[CPB] = {0.f, 0.f, 0.f, 0.f};
    int   cnt[CPB] = {0, 0, 0, 0};
    const int base = wv * (NV / 4);
    for (int i = 0; i < (NV / 4) / 64; ++i) {
        int n0  = base + i * 64;
        int idx = indices[n0 + lane];
#pragma unroll
        for (int c = 0; c < CPB; ++c) {
            unsigned long long m = __ballot(idx == kb + c);
            cnt[c] += __popcll(m);
            while (m) {
                int r = __ffsll((long long)m) - 1;
                m &= m - 1;
                acc[c] = __fadd_rn(acc[c], x_in[(size_t)(n0 + r) * ND + lane]);
            }
        }
    }
#pragma unroll
    for (int c = 0; c < CPB; ++c) {
        sacc[wv][c][lane] = acc[c];
        if (lane == 0) scnt[wv][c] = cnt[c];
    }
    __syncthreads();
    {
        const int c = wv, d = lane, k = kb + c;
        float s = __fadd_rn(__fadd_rn(__fadd_rn(sacc[0][c][d], sacc[1][c][d]),
                                      sacc[2][c][d]), sacc[3][c][d]);
        out_updw[(size_t)k * ND + d] =
            __fadd_rn(__fmul_rn(ema_w[(size_t)k * ND + d], DECAY_F), __fmul_rn(OMD_F, s));
        if (d == 0) {
            int ctot = scnt[0][c] + scnt[1][c] + scnt[2][c] + scnt[3][c];
            float uc = __fadd_rn(__fmul_rn(ema_cs[k], DECAY_F), __fmul_rn(OMD_F, (float)ctot));
            ucraw[k] = uc;
            atomicAdd(n_acc, uc);
            if (ctot > 0) atomicAdd(usage, 1.0f);
        }
    }
}

// ---------------------------------------------------------------------------
// Kernel 4: finalize — normalize cluster sizes, upd_embeddings, scalars.
// ---------------------------------------------------------------------------
__global__ __launch_bounds__(256) void vq_final(
    const float* __restrict__ ucraw, const float* __restrict__ n_acc,
    const float* __restrict__ usage, const double* __restrict__ loss_acc,
    const float* __restrict__ out_updw, float* __restrict__ out_upde,
    float* __restrict__ out_uc, float* __restrict__ out_usage,
    float* __restrict__ out_loss)
{
    int gid = blockIdx.x * 256 + threadIdx.x;
    int k = gid >> 6, d = gid & 63;
    float n_tot = *n_acc;
    float ucf = __fmul_rn(__fdiv_rn(__fadd_rn(ucraw[k], EPS_F), __fadd_rn(n_tot, KEPS_F)), n_tot);
    out_upde[gid] = __fdiv_rn(out_updw[gid], __fadd_rn(ucf, EPS_F));
    if (d == 0) out_uc[k] = ucf;
    if (gid == 0) {
        *out_usage = __fdiv_rn(*usage, 1024.0f);
        *out_loss  = (float)(*loss_acc / 8388608.0);
    }
}

// ---------------------------------------------------------------------------
extern "C" void kernel_launch(void* const* d_in, const int* in_sizes, int n_in,
                              void* d_out, int out_size, void* d_ws, size_t ws_size,
                              hipStream_t stream)
{
    const float* x_in   = (const float*)d_in[0];
    const float* emb    = (const float*)d_in[1];
    const float* ema_cs = (const float*)d_in[2];
    const float* ema_w  = (const float*)d_in[3];

    float* out_qf    = (float*)d_out;                    // [NV*64]
    float* out_enc   = out_qf + (size_t)NV * ND;         // [NV*1024]
    float* out_usage = out_enc + (size_t)NV * NK;        // [1]
    float* out_loss  = out_usage + 1;                    // [1]
    float* out_upde  = out_loss + 1;                     // [1024*64]
    float* out_uc    = out_upde + (size_t)NK * ND;       // [1024]
    float* out_updw  = out_uc + NK;                      // [1024*64]

    char* ws = (char*)d_ws;
    float*  ws_csq   = (float*)(ws);
    float*  ws_ucraw = (float*)(ws + 4096);
    float*  ws_nacc  = (float*)(ws + 8192);
    float*  ws_usage = (float*)(ws + 8196);
    double* ws_loss  = (double*)(ws + 8200);
    int*    ws_idx   = (int*)(ws + 8224);

    vq_prep<<<4, 256, 0, stream>>>(emb, ws_csq, ws_nacc, ws_usage, ws_loss);
    vq_assign<<<NV / NROWS_BLK, 256, 0, stream>>>(x_in, emb, ws_csq, out_qf, out_enc, ws_idx, ws_loss);
    vq_segsum<<<NK / CPB, 256, 0, stream>>>(x_in, ws_idx, ema_w, ema_cs, out_updw, ws_ucraw, ws_nacc, ws_usage);
    vq_final<<<256, 256, 0, stream>>>(ws_ucraw, ws_nacc, ws_usage, ws_loss, out_updw, out_upde, out_uc, out_usage, out_loss);
}

// Round 3
// 599.188 us; speedup vs baseline: 2.2043x; 2.2043x over previous
//
#include <hip/hip_runtime.h>
#include <hip/hip_bf16.h>

#define NK 1024        // codebook size
#define ND 64          // embedding dim
#define NV 131072      // 32*64*64 input vectors
#define BR 128         // rows per assign block
#define LDST 68        // padded LDS row stride (floats, 16B-aligned, bank-spread)
#define DECAY_F 0.99f
#define OMD_F 0.01f    // fl32(1.0 - 0.99) == fl32(0.01)
#define EPS_F 1e-5f
#define KEPS_F 0.01024f // fl32(1024 * 1e-5)

// ---- ws layout (bytes) ----
// 0      : csq[1024]    f32
// 4096   : cnt[1024]    i32
// 8192   : base[1024]   i32
// 12288  : cursor[1024] i32
// 16384  : ucf[1024]    f32
// 20480  : loss         f64
// 24576  : idx[NV]      i32 (512 KB)
// 548864 : rows[NV]     i32 (512 KB)

// ---------------------------------------------------------------------------
// Kernel 1: codebook_sq (numpy pairwise-8 rounding); zero cnt + loss.
// ---------------------------------------------------------------------------
__global__ __launch_bounds__(256) void vq_prep(const float* __restrict__ emb,
                                               float* __restrict__ csq,
                                               int* __restrict__ cnt,
                                               double* loss)
{
    int k = blockIdx.x * 256 + threadIdx.x;
    cnt[k] = 0;
    if (k == 0) *loss = 0.0;
    float p[ND];
    const float4* e4 = reinterpret_cast<const float4*>(emb + (size_t)k * ND);
#pragma unroll
    for (int i = 0; i < 16; ++i) {
        float4 v = e4[i];
        p[4*i+0] = __fmul_rn(v.x, v.x);
        p[4*i+1] = __fmul_rn(v.y, v.y);
        p[4*i+2] = __fmul_rn(v.z, v.z);
        p[4*i+3] = __fmul_rn(v.w, v.w);
    }
    float r[8];
#pragma unroll
    for (int j = 0; j < 8; ++j) r[j] = p[j];
#pragma unroll
    for (int i = 8; i < ND; i += 8)
#pragma unroll
        for (int j = 0; j < 8; ++j) r[j] = __fadd_rn(r[j], p[i+j]);
    csq[k] = __fadd_rn(__fadd_rn(__fadd_rn(r[0], r[1]), __fadd_rn(r[2], r[3])),
                       __fadd_rn(__fadd_rn(r[4], r[5]), __fadd_rn(r[6], r[7])));
}

// ---------------------------------------------------------------------------
// Kernel 2: register-tiled fp32 GEMM + fused argmin.
// 256 threads, 128 rows/block, 8 code-tiles of 128. Thread (tx=tid&15,
// ty=tid>>4) owns rows {ty+16i} and codes {tx+16j}: 8x8 dot tile, so each
// ds_read_b128 feeds 16 lane-FMAs. Interleaved encodings zero-fill;
// LDS reduction with exact first-index tie-break; qf/loss epilogue.
// ---------------------------------------------------------------------------
__global__ __launch_bounds__(256, 2) void vq_assign(
    const float* __restrict__ x_in, const float* __restrict__ emb,
    const float* __restrict__ csq, float* __restrict__ out_qf,
    float* __restrict__ out_enc, int* __restrict__ indices,
    int* __restrict__ cnt, double* __restrict__ loss_acc)
{
    __shared__ __align__(16) float xs[BR * LDST];
    __shared__ __align__(16) float es[BR * LDST];
    __shared__ float isq_s[BR];
    __shared__ float csq_s[128];
    __shared__ double lds_ls[4];

    const int tid  = threadIdx.x;
    const int lane = tid & 63;
    const int wv   = tid >> 6;
    const int tx   = tid & 15;
    const int ty   = tid >> 4;
    const size_t rowbase = (size_t)blockIdx.x * BR;

    // stage x tile (coalesced float4 copy)
    {
        const float4* src = reinterpret_cast<const float4*>(x_in + rowbase * ND);
#pragma unroll
        for (int it = 0; it < 8; ++it) {
            int f = tid + it * 256;
            float4 v = src[f];
            int row = f >> 4, col = f & 15;
            *reinterpret_cast<float4*>(&xs[row * LDST + col * 4]) = v;
        }
    }
    __syncthreads();

    // isq per row, numpy pairwise-8 order
    if (tid < BR) {
        const float* xr = &xs[tid * LDST];
        float r[8];
#pragma unroll
        for (int j = 0; j < 8; ++j) r[j] = __fmul_rn(xr[j], xr[j]);
#pragma unroll
        for (int i = 8; i < ND; i += 8)
#pragma unroll
            for (int j = 0; j < 8; ++j)
                r[j] = __fadd_rn(r[j], __fmul_rn(xr[i+j], xr[i+j]));
        isq_s[tid] = __fadd_rn(__fadd_rn(__fadd_rn(r[0], r[1]), __fadd_rn(r[2], r[3])),
                               __fadd_rn(__fadd_rn(r[4], r[5]), __fadd_rn(r[6], r[7])));
    }

    float best[8];
    int   bestk[8];
#pragma unroll
    for (int i = 0; i < 8; ++i) { best[i] = 3.4e38f; bestk[i] = 0; }

    for (int t = 0; t < 8; ++t) {
        // stage 128-code tile + csq
        {
            const float4* src = reinterpret_cast<const float4*>(emb + (size_t)t * 128 * ND);
#pragma unroll
            for (int it = 0; it < 8; ++it) {
                int f = tid + it * 256;
                float4 v = src[f];
                int row = f >> 4, col = f & 15;
                *reinterpret_cast<float4*>(&es[row * LDST + col * 4]) = v;
            }
            if (tid < 128) csq_s[tid] = csq[t * 128 + tid];
        }
        __syncthreads();

        float acc[8][8];
#pragma unroll
        for (int i = 0; i < 8; ++i)
#pragma unroll
            for (int j = 0; j < 8; ++j) acc[i][j] = 0.f;

        for (int ch = 0; ch < 16; ++ch) {
            float4 xf[8], ef[8];
#pragma unroll
            for (int i = 0; i < 8; ++i)
                xf[i] = *reinterpret_cast<const float4*>(&xs[(ty + 16*i) * LDST + ch * 4]);
#pragma unroll
            for (int j = 0; j < 8; ++j)
                ef[j] = *reinterpret_cast<const float4*>(&es[(tx + 16*j) * LDST + ch * 4]);
#pragma unroll
            for (int i = 0; i < 8; ++i) {
#pragma unroll
                for (int j = 0; j < 8; ++j) {
                    float a = acc[i][j];
                    a = __builtin_fmaf(xf[i].x, ef[j].x, a);
                    a = __builtin_fmaf(xf[i].y, ef[j].y, a);
                    a = __builtin_fmaf(xf[i].z, ef[j].z, a);
                    a = __builtin_fmaf(xf[i].w, ef[j].w, a);
                    acc[i][j] = a;
                }
            }
        }

        // compare (codes ascend with j and t -> strict < keeps first index)
#pragma unroll
        for (int i = 0; i < 8; ++i) {
            float isq = isq_s[ty + 16*i];
#pragma unroll
            for (int j = 0; j < 8; ++j) {
                float dist = __fsub_rn(__fadd_rn(isq, csq_s[tx + 16*j]),
                                       __fmul_rn(2.0f, acc[i][j]));
                if (dist < best[i]) { best[i] = dist; bestk[i] = t * 128 + tx + 16*j; }
            }
        }

        // interleaved encodings zero-fill: 16 rows per tile, 4 per wave
        {
            int rl = t * 16 + wv * 4;
#pragma unroll
            for (int rr = 0; rr < 4; ++rr) {
                float4* dst = reinterpret_cast<float4*>(out_enc + (rowbase + rl + rr) * NK);
                float4 z = make_float4(0.f, 0.f, 0.f, 0.f);
#pragma unroll
                for (int jj = 0; jj < 4; ++jj) dst[jj * 64 + lane] = z;
            }
        }
        __syncthreads();
    }

    // cross-thread argmin reduction (overlay scratch on es — tiles done)
    float* red_d = es;
    int*   red_i = reinterpret_cast<int*>(es + 2048);
#pragma unroll
    for (int i = 0; i < 8; ++i) {
        red_d[(ty + 16*i) * 16 + tx] = best[i];
        red_i[(ty + 16*i) * 16 + tx] = bestk[i];
    }
    __syncthreads();
    if (tid < BR) {
        float bd = red_d[tid * 16];
        int   bk = red_i[tid * 16];
#pragma unroll
        for (int c = 1; c < 16; ++c) {
            float d  = red_d[tid * 16 + c];
            int   k2 = red_i[tid * 16 + c];
            if (d < bd || (d == bd && k2 < bk)) { bd = d; bk = k2; }
        }
        size_t grow = rowbase + tid;
        indices[grow] = bk;
        out_enc[grow * NK + bk] = 1.0f;   // zeros drained at prior barrier
        atomicAdd(&cnt[bk], 1);
        red_i[tid * 16] = bk;             // publish for epilogue
    }
    __syncthreads();

    // epilogue: quantized_flow + loss; x from LDS, e from global (L2-hot)
    float lsum = 0.f;
    for (int r = 0; r < 32; ++r) {
        int rl = wv * 32 + r;
        int kr = red_i[rl * 16];
        size_t grow = rowbase + rl;
        float xv = xs[rl * LDST + lane];
        float ev = emb[(size_t)kr * ND + lane];
        out_qf[grow * ND + lane] = __fadd_rn(xv, __fsub_rn(ev, xv));
        float dd = __fsub_rn(xv, ev);
        lsum = __builtin_fmaf(dd, dd, lsum);
    }
    double ls = (double)lsum;
#pragma unroll
    for (int off = 32; off >= 1; off >>= 1) ls += __shfl_xor(ls, off, 64);
    if (lane == 0) lds_ls[wv] = ls;
    __syncthreads();
    if (tid == 0)
        atomicAdd(loss_acc, (lds_ls[0] + lds_ls[1]) + (lds_ls[2] + lds_ls[3]));
}

// ---------------------------------------------------------------------------
// Kernel 3: scan — upd_cluster (exact numpy pairwise n-sum), usage, loss,
// prefix offsets for the scatter lists.
// ---------------------------------------------------------------------------
__global__ __launch_bounds__(256) void vq_scan(
    const int* __restrict__ cnt, const float* __restrict__ ema_cs,
    const double* __restrict__ loss_acc, float* __restrict__ ucf_ws,
    int* __restrict__ base, int* __restrict__ cursor,
    float* __restrict__ out_uc, float* __restrict__ out_usage,
    float* __restrict__ out_loss)
{
    __shared__ float uc_s[1024];
    __shared__ float part[8];
    __shared__ int   csum[8];
    __shared__ int   usage_s;
    __shared__ float n_s;
    const int tid = threadIdx.x;
    if (tid == 0) usage_s = 0;
    __syncthreads();

    int ucount = 0;
    for (int it = 0; it < 4; ++it) {
        int k = tid + it * 256;
        int c = cnt[k];
        if (c > 0) ucount++;
        uc_s[k] = __fadd_rn(__fmul_rn(ema_cs[k], DECAY_F), __fmul_rn(OMD_F, (float)c));
    }
    atomicAdd(&usage_s, ucount);
    __syncthreads();

    if (tid < 8) {   // numpy pairwise: 8 base-128 blocks
        const float* u = &uc_s[tid * 128];
        float r[8];
#pragma unroll
        for (int j = 0; j < 8; ++j) r[j] = u[j];
        for (int i = 8; i < 128; i += 8)
#pragma unroll
            for (int j = 0; j < 8; ++j) r[j] = __fadd_rn(r[j], u[i+j]);
        part[tid] = __fadd_rn(__fadd_rn(__fadd_rn(r[0], r[1]), __fadd_rn(r[2], r[3])),
                              __fadd_rn(__fadd_rn(r[4], r[5]), __fadd_rn(r[6], r[7])));
        int s = 0;
        for (int i = 0; i < 128; ++i) s += cnt[tid * 128 + i];
        csum[tid] = s;
    }
    __syncthreads();
    if (tid == 0) {
        n_s = __fadd_rn(__fadd_rn(__fadd_rn(part[0], part[1]), __fadd_rn(part[2], part[3])),
                        __fadd_rn(__fadd_rn(part[4], part[5]), __fadd_rn(part[6], part[7])));
        *out_usage = __fdiv_rn((float)usage_s, 1024.0f);
        *out_loss  = (float)(*loss_acc / 8388608.0);
    }
    __syncthreads();

    const float n = n_s;
    for (int it = 0; it < 4; ++it) {
        int k = tid + it * 256;
        float ucfv = __fmul_rn(__fdiv_rn(__fadd_rn(uc_s[k], EPS_F), __fadd_rn(n, KEPS_F)), n);
        out_uc[k] = ucfv;
        ucf_ws[k] = ucfv;
    }
    if (tid < 8) {
        int run = 0;
        for (int t2 = 0; t2 < tid; ++t2) run += csum[t2];
        for (int i = 0; i < 128; ++i) {
            int k = tid * 128 + i;
            base[k] = run; cursor[k] = run;
            run += cnt[k];
        }
    }
}

// ---------------------------------------------------------------------------
// Kernel 4: scatter row ids into per-code lists.
// ---------------------------------------------------------------------------
__global__ __launch_bounds__(256) void vq_scatter(
    const int* __restrict__ idx, int* __restrict__ cursor, int* __restrict__ rows)
{
    int i = blockIdx.x * 256 + threadIdx.x;
    int k = idx[i];
    int slot = atomicAdd(&cursor[k], 1);
    rows[slot] = i;
}

// ---------------------------------------------------------------------------
// Kernel 5: gather — per-code row-list sum, write upd_ema_w + upd_embeddings.
// One wave per code (4 codes/block), lane = dim.
// ---------------------------------------------------------------------------
__global__ __launch_bounds__(256) void vq_gather(
    const float* __restrict__ x_in, const int* __restrict__ rows,
    const int* __restrict__ cnt, const int* __restrict__ base,
    const float* __restrict__ ucf, const float* __restrict__ ema_w,
    float* __restrict__ out_updw, float* __restrict__ out_upde)
{
    const int k    = blockIdx.x * 4 + (threadIdx.x >> 6);
    const int lane = threadIdx.x & 63;
    const int c = cnt[k], b = base[k];
    float a0 = 0.f, a1 = 0.f, a2 = 0.f, a3 = 0.f;
    int i = 0;
    for (; i + 4 <= c; i += 4) {
        int r0 = rows[b+i], r1 = rows[b+i+1], r2 = rows[b+i+2], r3 = rows[b+i+3];
        a0 = __fadd_rn(a0, x_in[(size_t)r0 * ND + lane]);
        a1 = __fadd_rn(a1, x_in[(size_t)r1 * ND + lane]);
        a2 = __fadd_rn(a2, x_in[(size_t)r2 * ND + lane]);
        a3 = __fadd_rn(a3, x_in[(size_t)r3 * ND + lane]);
    }
    for (; i < c; ++i)
        a0 = __fadd_rn(a0, x_in[(size_t)rows[b+i] * ND + lane]);
    float s = __fadd_rn(__fadd_rn(a0, a1), __fadd_rn(a2, a3));
    float w = __fadd_rn(__fmul_rn(ema_w[(size_t)k * ND + lane], DECAY_F), __fmul_rn(OMD_F, s));
    out_updw[(size_t)k * ND + lane] = w;
    out_upde[(size_t)k * ND + lane] = __fdiv_rn(w, __fadd_rn(ucf[k], EPS_F));
}

// ---------------------------------------------------------------------------
extern "C" void kernel_launch(void* const* d_in, const int* in_sizes, int n_in,
                              void* d_out, int out_size, void* d_ws, size_t ws_size,
                              hipStream_t stream)
{
    const float* x_in   = (const float*)d_in[0];
    const float* emb    = (const float*)d_in[1];
    const float* ema_cs = (const float*)d_in[2];
    const float* ema_w  = (const float*)d_in[3];

    float* out_qf    = (float*)d_out;                    // [NV*64]
    float* out_enc   = out_qf + (size_t)NV * ND;         // [NV*1024]
    float* out_usage = out_enc + (size_t)NV * NK;        // [1]
    float* out_loss  = out_usage + 1;                    // [1]
    float* out_upde  = out_loss + 1;                     // [1024*64]
    float* out_uc    = out_upde + (size_t)NK * ND;       // [1024]
    float* out_updw  = out_uc + NK;                      // [1024*64]

    char* ws = (char*)d_ws;
    float*  ws_csq    = (float*)(ws);
    int*    ws_cnt    = (int*)(ws + 4096);
    int*    ws_base   = (int*)(ws + 8192);
    int*    ws_cursor = (int*)(ws + 12288);
    float*  ws_ucf    = (float*)(ws + 16384);
    double* ws_loss   = (double*)(ws + 20480);
    int*    ws_idx    = (int*)(ws + 24576);
    int*    ws_rows   = (int*)(ws + 24576 + (size_t)NV * 4);

    vq_prep<<<4, 256, 0, stream>>>(emb, ws_csq, ws_cnt, ws_loss);
    vq_assign<<<NV / BR, 256, 0, stream>>>(x_in, emb, ws_csq, out_qf, out_enc,
                                           ws_idx, ws_cnt, ws_loss);
    vq_scan<<<1, 256, 0, stream>>>(ws_cnt, ema_cs, ws_loss, ws_ucf, ws_base,
                                   ws_cursor, out_uc, out_usage, out_loss);
    vq_scatter<<<NV / 256, 256, 0, stream>>>(ws_idx, ws_cursor, ws_rows);
    vq_gather<<<NK / 4, 256, 0, stream>>>(x_in, ws_rows, ws_cnt, ws_base,
                                          ws_ucf, ema_w, out_updw, out_upde);
}

// Round 4
// 492.946 us; speedup vs baseline: 2.6794x; 1.2155x over previous
//
#include <hip/hip_runtime.h>
#include <hip/hip_bf16.h>

#define NK 1024        // codebook size
#define ND 64          // embedding dim
#define NV 131072      // 32*64*64 input vectors
#define BR 128         // rows per assign block
#define DECAY_F 0.99f
#define OMD_F 0.01f
#define EPS_F 1e-5f
#define KEPS_F 0.01024f // fl32(1024 * 1e-5)

typedef const __attribute__((address_space(1))) void* gas1_t;
typedef __attribute__((address_space(3))) void* las3_t;
#define GLOAD_LDS16(gp, lp) \
    __builtin_amdgcn_global_load_lds((gas1_t)(gp), (las3_t)(lp), 16, 0, 0)

// ---- ws layout (bytes) ----
// 0      : csq[1024]    f32
// 4096   : cnt[1024]    i32
// 8192   : base[1024]   i32
// 12288  : cursor[1024] i32
// 16384  : ucf[1024]    f32
// 20480  : loss         f64
// 24576  : idx[NV]      i32 (512 KB)
// 548864 : rows[NV]     i32 (512 KB)

// ---------------------------------------------------------------------------
// Kernel 1: codebook_sq (numpy pairwise-8 rounding); zero cnt + loss.
// ---------------------------------------------------------------------------
__global__ __launch_bounds__(256) void vq_prep(const float* __restrict__ emb,
                                               float* __restrict__ csq,
                                               int* __restrict__ cnt,
                                               double* loss)
{
    int k = blockIdx.x * 256 + threadIdx.x;
    cnt[k] = 0;
    if (k == 0) *loss = 0.0;
    float p[ND];
    const float4* e4 = reinterpret_cast<const float4*>(emb + (size_t)k * ND);
#pragma unroll
    for (int i = 0; i < 16; ++i) {
        float4 v = e4[i];
        p[4*i+0] = __fmul_rn(v.x, v.x);
        p[4*i+1] = __fmul_rn(v.y, v.y);
        p[4*i+2] = __fmul_rn(v.z, v.z);
        p[4*i+3] = __fmul_rn(v.w, v.w);
    }
    float r[8];
#pragma unroll
    for (int j = 0; j < 8; ++j) r[j] = p[j];
#pragma unroll
    for (int i = 8; i < ND; i += 8)
#pragma unroll
        for (int j = 0; j < 8; ++j) r[j] = __fadd_rn(r[j], p[i+j]);
    csq[k] = __fadd_rn(__fadd_rn(__fadd_rn(r[0], r[1]), __fadd_rn(r[2], r[3])),
                       __fadd_rn(__fadd_rn(r[4], r[5]), __fadd_rn(r[6], r[7])));
}

// ---------------------------------------------------------------------------
// Kernel 2: register-tiled fp32 GEMM + fused argmin.
// Staging via async global_load_lds (16B/lane) into XOR-swizzled linear LDS:
// element (row, chunk) stored at chunk^(row&7); global source pre-swizzled,
// every LDS read applies the same XOR. Logical d-order (and thus all FP
// rounding) identical to the passing round-3 kernel.
// ---------------------------------------------------------------------------
__global__ __launch_bounds__(256, 2) void vq_assign(
    const float* __restrict__ x_in, const float* __restrict__ emb,
    const float* __restrict__ csq, float* __restrict__ out_qf,
    float* __restrict__ out_enc, int* __restrict__ indices,
    int* __restrict__ cnt, double* __restrict__ loss_acc)
{
    __shared__ __align__(16) float xs[BR * ND];    // 32 KB, swizzled
    __shared__ __align__(16) float es[128 * ND];   // 32 KB, swizzled
    __shared__ float csq_s[NK];
    __shared__ float isq_s[BR];
    __shared__ double lds_ls[4];

    const int tid  = threadIdx.x;
    const int lane = tid & 63;
    const int wv   = tid >> 6;
    const int tx   = tid & 15;
    const int ty   = tid >> 4;
    const int txs  = tx & 7;
    const int tys  = ty & 7;
    const size_t rowbase = (size_t)blockIdx.x * BR;

    // ---- stage xs + es(tile 0) via async DMA; csq via regular copy ----
#pragma unroll
    for (int c = 0; c < 8; ++c) {
        int f = tid + c * 256;
        int row = f >> 4, ch = f & 15;
        int sch = ch ^ (row & 7);
        GLOAD_LDS16(x_in + rowbase * ND + row * ND + sch * 4, &xs[f * 4]);
    }
#pragma unroll
    for (int c = 0; c < 8; ++c) {
        int f = tid + c * 256;
        int row = f >> 4, ch = f & 15;
        int sch = ch ^ (row & 7);
        GLOAD_LDS16(emb + (size_t)row * ND + sch * 4, &es[f * 4]);
    }
#pragma unroll
    for (int c = 0; c < 4; ++c) csq_s[tid + c * 256] = csq[tid + c * 256];
    __syncthreads();

    // ---- isq per row (numpy pairwise-8 order, swizzled reads) ----
    if (tid < BR) {
        const int rs = tid & 7;
        const float* xr = &xs[tid * ND];
        float r[8];
        {
            float4 a = *(const float4*)&xr[(0 ^ rs) * 4];
            float4 b = *(const float4*)&xr[(1 ^ rs) * 4];
            r[0] = __fmul_rn(a.x, a.x); r[1] = __fmul_rn(a.y, a.y);
            r[2] = __fmul_rn(a.z, a.z); r[3] = __fmul_rn(a.w, a.w);
            r[4] = __fmul_rn(b.x, b.x); r[5] = __fmul_rn(b.y, b.y);
            r[6] = __fmul_rn(b.z, b.z); r[7] = __fmul_rn(b.w, b.w);
        }
#pragma unroll
        for (int g = 1; g < 8; ++g) {
            float4 a = *(const float4*)&xr[((2*g)   ^ rs) * 4];
            float4 b = *(const float4*)&xr[((2*g+1) ^ rs) * 4];
            r[0] = __fadd_rn(r[0], __fmul_rn(a.x, a.x));
            r[1] = __fadd_rn(r[1], __fmul_rn(a.y, a.y));
            r[2] = __fadd_rn(r[2], __fmul_rn(a.z, a.z));
            r[3] = __fadd_rn(r[3], __fmul_rn(a.w, a.w));
            r[4] = __fadd_rn(r[4], __fmul_rn(b.x, b.x));
            r[5] = __fadd_rn(r[5], __fmul_rn(b.y, b.y));
            r[6] = __fadd_rn(r[6], __fmul_rn(b.z, b.z));
            r[7] = __fadd_rn(r[7], __fmul_rn(b.w, b.w));
        }
        isq_s[tid] = __fadd_rn(__fadd_rn(__fadd_rn(r[0], r[1]), __fadd_rn(r[2], r[3])),
                               __fadd_rn(__fadd_rn(r[4], r[5]), __fadd_rn(r[6], r[7])));
    }

    float best[8];
    int   bestk[8];
#pragma unroll
    for (int i = 0; i < 8; ++i) { best[i] = 3.4e38f; bestk[i] = 0; }

    for (int t = 0; t < 8; ++t) {
        float acc[8][8];
#pragma unroll
        for (int i = 0; i < 8; ++i)
#pragma unroll
            for (int j = 0; j < 8; ++j) acc[i][j] = 0.f;

        for (int ch = 0; ch < 16; ++ch) {
            const int xo = (ch ^ tys) * 4;
            const int eo = (ch ^ txs) * 4;
            float4 xf[8], ef[8];
#pragma unroll
            for (int i = 0; i < 8; ++i)
                xf[i] = *(const float4*)&xs[(ty + 16*i) * ND + xo];
#pragma unroll
            for (int j = 0; j < 8; ++j)
                ef[j] = *(const float4*)&es[(tx + 16*j) * ND + eo];
#pragma unroll
            for (int i = 0; i < 8; ++i) {
#pragma unroll
                for (int j = 0; j < 8; ++j) {
                    float a = acc[i][j];
                    a = __builtin_fmaf(xf[i].x, ef[j].x, a);
                    a = __builtin_fmaf(xf[i].y, ef[j].y, a);
                    a = __builtin_fmaf(xf[i].z, ef[j].z, a);
                    a = __builtin_fmaf(xf[i].w, ef[j].w, a);
                    acc[i][j] = a;
                }
            }
        }

        // compare (codes ascend with j and t -> strict < keeps first index)
#pragma unroll
        for (int i = 0; i < 8; ++i) {
            float isq = isq_s[ty + 16*i];
#pragma unroll
            for (int j = 0; j < 8; ++j) {
                float dist = __fsub_rn(__fadd_rn(isq, csq_s[t * 128 + tx + 16*j]),
                                       __fmul_rn(2.0f, acc[i][j]));
                if (dist < best[i]) { best[i] = dist; bestk[i] = t * 128 + tx + 16*j; }
            }
        }

        // interleaved encodings zero-fill: 16 rows per tile, 4 per wave
        {
            int rl = t * 16 + wv * 4;
#pragma unroll
            for (int rr = 0; rr < 4; ++rr) {
                float4* dst = reinterpret_cast<float4*>(out_enc + (rowbase + rl + rr) * NK);
                float4 z = make_float4(0.f, 0.f, 0.f, 0.f);
#pragma unroll
                for (int jj = 0; jj < 4; ++jj) dst[jj * 64 + lane] = z;
            }
        }

        __syncthreads();            // all waves done reading es tile t
        if (t < 7) {
#pragma unroll
            for (int c = 0; c < 8; ++c) {
                int f = tid + c * 256;
                int row = f >> 4, ch = f & 15;
                int sch = ch ^ (row & 7);
                GLOAD_LDS16(emb + (size_t)(t + 1) * 128 * ND + row * ND + sch * 4,
                            &es[f * 4]);
            }
        }
        __syncthreads();            // DMA drained: tile t+1 present
    }

    // ---- cross-thread argmin reduction (overlay scratch on es) ----
    float* red_d = es;
    int*   red_i = reinterpret_cast<int*>(es + 2048);
#pragma unroll
    for (int i = 0; i < 8; ++i) {
        red_d[(ty + 16*i) * 16 + tx] = best[i];
        red_i[(ty + 16*i) * 16 + tx] = bestk[i];
    }
    __syncthreads();
    if (tid < BR) {
        float bd = red_d[tid * 16];
        int   bk = red_i[tid * 16];
#pragma unroll
        for (int c = 1; c < 16; ++c) {
            float d  = red_d[tid * 16 + c];
            int   k2 = red_i[tid * 16 + c];
            if (d < bd || (d == bd && k2 < bk)) { bd = d; bk = k2; }
        }
        size_t grow = rowbase + tid;
        indices[grow] = bk;
        out_enc[grow * NK + bk] = 1.0f;   // zeros drained at prior barriers
        atomicAdd(&cnt[bk], 1);
        red_i[tid * 16] = bk;             // publish for epilogue
    }
    __syncthreads();

    // ---- epilogue: quantized_flow + loss ----
    float lsum = 0.f;
    const int lsw = ((lane >> 2)) ;     // chunk of element `lane`
    for (int r = 0; r < 32; ++r) {
        int rl = wv * 32 + r;
        int kr = red_i[rl * 16];
        size_t grow = rowbase + rl;
        float xv = xs[rl * ND + ((lsw ^ (rl & 7)) << 2) + (lane & 3)];
        float ev = emb[(size_t)kr * ND + lane];
        out_qf[grow * ND + lane] = __fadd_rn(xv, __fsub_rn(ev, xv));
        float dd = __fsub_rn(xv, ev);
        lsum = __builtin_fmaf(dd, dd, lsum);
    }
    double ls = (double)lsum;
#pragma unroll
    for (int off = 32; off >= 1; off >>= 1) ls += __shfl_xor(ls, off, 64);
    if (lane == 0) lds_ls[wv] = ls;
    __syncthreads();
    if (tid == 0)
        atomicAdd(loss_acc, (lds_ls[0] + lds_ls[1]) + (lds_ls[2] + lds_ls[3]));
}

// ---------------------------------------------------------------------------
// Kernel 3: scan — upd_cluster (exact numpy pairwise n-sum), usage, loss,
// prefix offsets for the scatter lists.
// ---------------------------------------------------------------------------
__global__ __launch_bounds__(256) void vq_scan(
    const int* __restrict__ cnt, const float* __restrict__ ema_cs,
    const double* __restrict__ loss_acc, float* __restrict__ ucf_ws,
    int* __restrict__ base, int* __restrict__ cursor,
    float* __restrict__ out_uc, float* __restrict__ out_usage,
    float* __restrict__ out_loss)
{
    __shared__ float uc_s[1024];
    __shared__ float part[8];
    __shared__ int   csum[8];
    __shared__ int   usage_s;
    __shared__ float n_s;
    const int tid = threadIdx.x;
    if (tid == 0) usage_s = 0;
    __syncthreads();

    int ucount = 0;
    for (int it = 0; it < 4; ++it) {
        int k = tid + it * 256;
        int c = cnt[k];
        if (c > 0) ucount++;
        uc_s[k] = __fadd_rn(__fmul_rn(ema_cs[k], DECAY_F), __fmul_rn(OMD_F, (float)c));
    }
    atomicAdd(&usage_s, ucount);
    __syncthreads();

    if (tid < 8) {   // numpy pairwise: 8 base-128 blocks
        const float* u = &uc_s[tid * 128];
        float r[8];
#pragma unroll
        for (int j = 0; j < 8; ++j) r[j] = u[j];
        for (int i = 8; i < 128; i += 8)
#pragma unroll
            for (int j = 0; j < 8; ++j) r[j] = __fadd_rn(r[j], u[i+j]);
        part[tid] = __fadd_rn(__fadd_rn(__fadd_rn(r[0], r[1]), __fadd_rn(r[2], r[3])),
                              __fadd_rn(__fadd_rn(r[4], r[5]), __fadd_rn(r[6], r[7])));
        int s = 0;
        for (int i = 0; i < 128; ++i) s += cnt[tid * 128 + i];
        csum[tid] = s;
    }
    __syncthreads();
    if (tid == 0) {
        n_s = __fadd_rn(__fadd_rn(__fadd_rn(part[0], part[1]), __fadd_rn(part[2], part[3])),
                        __fadd_rn(__fadd_rn(part[4], part[5]), __fadd_rn(part[6], part[7])));
        *out_usage = __fdiv_rn((float)usage_s, 1024.0f);
        *out_loss  = (float)(*loss_acc / 8388608.0);
    }
    __syncthreads();

    const float n = n_s;
    for (int it = 0; it < 4; ++it) {
        int k = tid + it * 256;
        float ucfv = __fmul_rn(__fdiv_rn(__fadd_rn(uc_s[k], EPS_F), __fadd_rn(n, KEPS_F)), n);
        out_uc[k] = ucfv;
        ucf_ws[k] = ucfv;
    }
    if (tid < 8) {
        int run = 0;
        for (int t2 = 0; t2 < tid; ++t2) run += csum[t2];
        for (int i = 0; i < 128; ++i) {
            int k = tid * 128 + i;
            base[k] = run; cursor[k] = run;
            run += cnt[k];
        }
    }
}

// ---------------------------------------------------------------------------
// Kernel 4: scatter row ids into per-code lists.
// ---------------------------------------------------------------------------
__global__ __launch_bounds__(256) void vq_scatter(
    const int* __restrict__ idx, int* __restrict__ cursor, int* __restrict__ rows)
{
    int i = blockIdx.x * 256 + threadIdx.x;
    int k = idx[i];
    int slot = atomicAdd(&cursor[k], 1);
    rows[slot] = i;
}

// ---------------------------------------------------------------------------
// Kernel 5: gather — one block per code, 4 waves split the row list,
// LDS combine; write upd_ema_w + upd_embeddings. lane = dim.
// ---------------------------------------------------------------------------
__global__ __launch_bounds__(256) void vq_gather(
    const float* __restrict__ x_in, const int* __restrict__ rows,
    const int* __restrict__ cnt, const int* __restrict__ base,
    const float* __restrict__ ucf, const float* __restrict__ ema_w,
    float* __restrict__ out_updw, float* __restrict__ out_upde)
{
    __shared__ float sacc[4][64];
    const int k    = blockIdx.x;
    const int tid  = threadIdx.x;
    const int lane = tid & 63;
    const int wv   = tid >> 6;
    const int c = cnt[k], b = base[k];

    float a0 = 0.f, a1 = 0.f;
    int i = wv;
    for (; i + 4 < c; i += 8) {
        int r0 = rows[b + i];
        int r1 = rows[b + i + 4];
        a0 = __fadd_rn(a0, x_in[(size_t)r0 * ND + lane]);
        a1 = __fadd_rn(a1, x_in[(size_t)r1 * ND + lane]);
    }
    for (; i < c; i += 4)
        a0 = __fadd_rn(a0, x_in[(size_t)rows[b + i] * ND + lane]);
    sacc[wv][lane] = __fadd_rn(a0, a1);
    __syncthreads();
    if (tid < 64) {
        float s = __fadd_rn(__fadd_rn(sacc[0][tid], sacc[1][tid]),
                            __fadd_rn(sacc[2][tid], sacc[3][tid]));
        float w = __fadd_rn(__fmul_rn(ema_w[(size_t)k * ND + tid], DECAY_F),
                            __fmul_rn(OMD_F, s));
        out_updw[(size_t)k * ND + tid] = w;
        out_upde[(size_t)k * ND + tid] = __fdiv_rn(w, __fadd_rn(ucf[k], EPS_F));
    }
}

// ---------------------------------------------------------------------------
extern "C" void kernel_launch(void* const* d_in, const int* in_sizes, int n_in,
                              void* d_out, int out_size, void* d_ws, size_t ws_size,
                              hipStream_t stream)
{
    const float* x_in   = (const float*)d_in[0];
    const float* emb    = (const float*)d_in[1];
    const float* ema_cs = (const float*)d_in[2];
    const float* ema_w  = (const float*)d_in[3];

    float* out_qf    = (float*)d_out;                    // [NV*64]
    float* out_enc   = out_qf + (size_t)NV * ND;         // [NV*1024]
    float* out_usage = out_enc + (size_t)NV * NK;        // [1]
    float* out_loss  = out_usage + 1;                    // [1]
    float* out_upde  = out_loss + 1;                     // [1024*64]
    float* out_uc    = out_upde + (size_t)NK * ND;       // [1024]
    float* out_updw  = out_uc + NK;                      // [1024*64]

    char* ws = (char*)d_ws;
    float*  ws_csq    = (float*)(ws);
    int*    ws_cnt    = (int*)(ws + 4096);
    int*    ws_base   = (int*)(ws + 8192);
    int*    ws_cursor = (int*)(ws + 12288);
    float*  ws_ucf    = (float*)(ws + 16384);
    double* ws_loss   = (double*)(ws + 20480);
    int*    ws_idx    = (int*)(ws + 24576);
    int*    ws_rows   = (int*)(ws + 24576 + (size_t)NV * 4);

    vq_prep<<<4, 256, 0, stream>>>(emb, ws_csq, ws_cnt, ws_loss);
    vq_assign<<<NV / BR, 256, 0, stream>>>(x_in, emb, ws_csq, out_qf, out_enc,
                                           ws_idx, ws_cnt, ws_loss);
    vq_scan<<<1, 256, 0, stream>>>(ws_cnt, ema_cs, ws_loss, ws_ucf, ws_base,
                                   ws_cursor, out_uc, out_usage, out_loss);
    vq_scatter<<<NV / 256, 256, 0, stream>>>(ws_idx, ws_cursor, ws_rows);
    vq_gather<<<NK, 256, 0, stream>>>(x_in, ws_rows, ws_cnt, ws_base,
                                      ws_ucf, ema_w, out_updw, out_upde);
}

// Round 6
// 322.208 us; speedup vs baseline: 4.0992x; 1.5299x over previous
//
#include <hip/hip_runtime.h>
#include <hip/hip_bf16.h>

#define NK 1024        // codebook size
#define ND 64          // embedding dim
#define NV 131072      // 32*64*64 input vectors
#define BR 128         // rows per assign block
#define DECAY_F 0.99f
#define OMD_F 0.01f
#define EPS_F 1e-5f
#define KEPS_F 0.01024f // fl32(1024 * 1e-5)

typedef const __attribute__((address_space(1))) void* gas1_t;
typedef __attribute__((address_space(3))) void* las3_t;
#define GLOAD_LDS16(gp, lp) \
    __builtin_amdgcn_global_load_lds((gas1_t)(gp), (las3_t)(lp), 16, 0, 0)

// ---- ws layout (bytes) ----
// 0       : csq[1024]    f32
// 4096    : cnt[1024]    i32
// 8192    : base[1024]   i32
// 12288   : cursor[1024] i32
// 16384   : ucf[1024]    f32
// 20480   : loss         f64
// 24576   : idx[NV]      i32 (512 KB)
// 548864  : rows[NV]     i32 (512 KB)
// 1073152 : codes[NV]    i32 (512 KB)
// 1597440 : acc[65536]   f32 (256 KB)

// ---------------------------------------------------------------------------
// Kernel 1: codebook_sq (numpy pairwise-8 rounding); zero cnt/loss/acc.
// ---------------------------------------------------------------------------
__global__ __launch_bounds__(256) void vq_prep(const float* __restrict__ emb,
                                               float* __restrict__ csq,
                                               int* __restrict__ cnt,
                                               double* loss,
                                               float4* __restrict__ acc4)
{
    int k = blockIdx.x * 256 + threadIdx.x;
    cnt[k] = 0;
    if (k == 0) *loss = 0.0;
    float4 z = make_float4(0.f, 0.f, 0.f, 0.f);
#pragma unroll
    for (int i = 0; i < 16; ++i) acc4[k + i * 1024] = z;   // zero acc[65536]
    float p[ND];
    const float4* e4 = reinterpret_cast<const float4*>(emb + (size_t)k * ND);
#pragma unroll
    for (int i = 0; i < 16; ++i) {
        float4 v = e4[i];
        p[4*i+0] = __fmul_rn(v.x, v.x);
        p[4*i+1] = __fmul_rn(v.y, v.y);
        p[4*i+2] = __fmul_rn(v.z, v.z);
        p[4*i+3] = __fmul_rn(v.w, v.w);
    }
    float r[8];
#pragma unroll
    for (int j = 0; j < 8; ++j) r[j] = p[j];
#pragma unroll
    for (int i = 8; i < ND; i += 8)
#pragma unroll
        for (int j = 0; j < 8; ++j) r[j] = __fadd_rn(r[j], p[i+j]);
    csq[k] = __fadd_rn(__fadd_rn(__fadd_rn(r[0], r[1]), __fadd_rn(r[2], r[3])),
                       __fadd_rn(__fadd_rn(r[4], r[5]), __fadd_rn(r[6], r[7])));
}

// ---------------------------------------------------------------------------
// Kernel 2: register-tiled fp32 GEMM + fused argmin (UNCHANGED from round 4).
// ---------------------------------------------------------------------------
__global__ __launch_bounds__(256, 2) void vq_assign(
    const float* __restrict__ x_in, const float* __restrict__ emb,
    const float* __restrict__ csq, float* __restrict__ out_qf,
    float* __restrict__ out_enc, int* __restrict__ indices,
    int* __restrict__ cnt, double* __restrict__ loss_acc)
{
    __shared__ __align__(16) float xs[BR * ND];    // 32 KB, swizzled
    __shared__ __align__(16) float es[128 * ND];   // 32 KB, swizzled
    __shared__ float csq_s[NK];
    __shared__ float isq_s[BR];
    __shared__ double lds_ls[4];

    const int tid  = threadIdx.x;
    const int lane = tid & 63;
    const int wv   = tid >> 6;
    const int tx   = tid & 15;
    const int ty   = tid >> 4;
    const int txs  = tx & 7;
    const int tys  = ty & 7;
    const size_t rowbase = (size_t)blockIdx.x * BR;

    // ---- stage xs + es(tile 0) via async DMA; csq via regular copy ----
#pragma unroll
    for (int c = 0; c < 8; ++c) {
        int f = tid + c * 256;
        int row = f >> 4, ch = f & 15;
        int sch = ch ^ (row & 7);
        GLOAD_LDS16(x_in + rowbase * ND + row * ND + sch * 4, &xs[f * 4]);
    }
#pragma unroll
    for (int c = 0; c < 8; ++c) {
        int f = tid + c * 256;
        int row = f >> 4, ch = f & 15;
        int sch = ch ^ (row & 7);
        GLOAD_LDS16(emb + (size_t)row * ND + sch * 4, &es[f * 4]);
    }
#pragma unroll
    for (int c = 0; c < 4; ++c) csq_s[tid + c * 256] = csq[tid + c * 256];
    __syncthreads();

    // ---- isq per row (numpy pairwise-8 order, swizzled reads) ----
    if (tid < BR) {
        const int rs = tid & 7;
        const float* xr = &xs[tid * ND];
        float r[8];
        {
            float4 a = *(const float4*)&xr[(0 ^ rs) * 4];
            float4 b = *(const float4*)&xr[(1 ^ rs) * 4];
            r[0] = __fmul_rn(a.x, a.x); r[1] = __fmul_rn(a.y, a.y);
            r[2] = __fmul_rn(a.z, a.z); r[3] = __fmul_rn(a.w, a.w);
            r[4] = __fmul_rn(b.x, b.x); r[5] = __fmul_rn(b.y, b.y);
            r[6] = __fmul_rn(b.z, b.z); r[7] = __fmul_rn(b.w, b.w);
        }
#pragma unroll
        for (int g = 1; g < 8; ++g) {
            float4 a = *(const float4*)&xr[((2*g)   ^ rs) * 4];
            float4 b = *(const float4*)&xr[((2*g+1) ^ rs) * 4];
            r[0] = __fadd_rn(r[0], __fmul_rn(a.x, a.x));
            r[1] = __fadd_rn(r[1], __fmul_rn(a.y, a.y));
            r[2] = __fadd_rn(r[2], __fmul_rn(a.z, a.z));
            r[3] = __fadd_rn(r[3], __fmul_rn(a.w, a.w));
            r[4] = __fadd_rn(r[4], __fmul_rn(b.x, b.x));
            r[5] = __fadd_rn(r[5], __fmul_rn(b.y, b.y));
            r[6] = __fadd_rn(r[6], __fmul_rn(b.z, b.z));
            r[7] = __fadd_rn(r[7], __fmul_rn(b.w, b.w));
        }
        isq_s[tid] = __fadd_rn(__fadd_rn(__fadd_rn(r[0], r[1]), __fadd_rn(r[2], r[3])),
                               __fadd_rn(__fadd_rn(r[4], r[5]), __fadd_rn(r[6], r[7])));
    }

    float best[8];
    int   bestk[8];
#pragma unroll
    for (int i = 0; i < 8; ++i) { best[i] = 3.4e38f; bestk[i] = 0; }

    for (int t = 0; t < 8; ++t) {
        float acc[8][8];
#pragma unroll
        for (int i = 0; i < 8; ++i)
#pragma unroll
            for (int j = 0; j < 8; ++j) acc[i][j] = 0.f;

        for (int ch = 0; ch < 16; ++ch) {
            const int xo = (ch ^ tys) * 4;
            const int eo = (ch ^ txs) * 4;
            float4 xf[8], ef[8];
#pragma unroll
            for (int i = 0; i < 8; ++i)
                xf[i] = *(const float4*)&xs[(ty + 16*i) * ND + xo];
#pragma unroll
            for (int j = 0; j < 8; ++j)
                ef[j] = *(const float4*)&es[(tx + 16*j) * ND + eo];
#pragma unroll
            for (int i = 0; i < 8; ++i) {
#pragma unroll
                for (int j = 0; j < 8; ++j) {
                    float a = acc[i][j];
                    a = __builtin_fmaf(xf[i].x, ef[j].x, a);
                    a = __builtin_fmaf(xf[i].y, ef[j].y, a);
                    a = __builtin_fmaf(xf[i].z, ef[j].z, a);
                    a = __builtin_fmaf(xf[i].w, ef[j].w, a);
                    acc[i][j] = a;
                }
            }
        }

        // compare (codes ascend with j and t -> strict < keeps first index)
#pragma unroll
        for (int i = 0; i < 8; ++i) {
            float isq = isq_s[ty + 16*i];
#pragma unroll
            for (int j = 0; j < 8; ++j) {
                float dist = __fsub_rn(__fadd_rn(isq, csq_s[t * 128 + tx + 16*j]),
                                       __fmul_rn(2.0f, acc[i][j]));
                if (dist < best[i]) { best[i] = dist; bestk[i] = t * 128 + tx + 16*j; }
            }
        }

        // interleaved encodings zero-fill: 16 rows per tile, 4 per wave
        {
            int rl = t * 16 + wv * 4;
#pragma unroll
            for (int rr = 0; rr < 4; ++rr) {
                float4* dst = reinterpret_cast<float4*>(out_enc + (rowbase + rl + rr) * NK);
                float4 z = make_float4(0.f, 0.f, 0.f, 0.f);
#pragma unroll
                for (int jj = 0; jj < 4; ++jj) dst[jj * 64 + lane] = z;
            }
        }

        __syncthreads();            // all waves done reading es tile t
        if (t < 7) {
#pragma unroll
            for (int c = 0; c < 8; ++c) {
                int f = tid + c * 256;
                int row = f >> 4, ch = f & 15;
                int sch = ch ^ (row & 7);
                GLOAD_LDS16(emb + (size_t)(t + 1) * 128 * ND + row * ND + sch * 4,
                            &es[f * 4]);
            }
        }
        __syncthreads();            // DMA drained: tile t+1 present
    }

    // ---- cross-thread argmin reduction (overlay scratch on es) ----
    float* red_d = es;
    int*   red_i = reinterpret_cast<int*>(es + 2048);
#pragma unroll
    for (int i = 0; i < 8; ++i) {
        red_d[(ty + 16*i) * 16 + tx] = best[i];
        red_i[(ty + 16*i) * 16 + tx] = bestk[i];
    }
    __syncthreads();
    if (tid < BR) {
        float bd = red_d[tid * 16];
        int   bk = red_i[tid * 16];
#pragma unroll
        for (int c = 1; c < 16; ++c) {
            float d  = red_d[tid * 16 + c];
            int   k2 = red_i[tid * 16 + c];
            if (d < bd || (d == bd && k2 < bk)) { bd = d; bk = k2; }
        }
        size_t grow = rowbase + tid;
        indices[grow] = bk;
        out_enc[grow * NK + bk] = 1.0f;   // zeros drained at prior barriers
        atomicAdd(&cnt[bk], 1);
        red_i[tid * 16] = bk;             // publish for epilogue
    }
    __syncthreads();

    // ---- epilogue: quantized_flow + loss ----
    float lsum = 0.f;
    const int lsw = ((lane >> 2)) ;     // chunk of element `lane`
    for (int r = 0; r < 32; ++r) {
        int rl = wv * 32 + r;
        int kr = red_i[rl * 16];
        size_t grow = rowbase + rl;
        float xv = xs[rl * ND + ((lsw ^ (rl & 7)) << 2) + (lane & 3)];
        float ev = emb[(size_t)kr * ND + lane];
        out_qf[grow * ND + lane] = __fadd_rn(xv, __fsub_rn(ev, xv));
        float dd = __fsub_rn(xv, ev);
        lsum = __builtin_fmaf(dd, dd, lsum);
    }
    double ls = (double)lsum;
#pragma unroll
    for (int off = 32; off >= 1; off >>= 1) ls += __shfl_xor(ls, off, 64);
    if (lane == 0) lds_ls[wv] = ls;
    __syncthreads();
    if (tid == 0)
        atomicAdd(loss_acc, (lds_ls[0] + lds_ls[1]) + (lds_ls[2] + lds_ls[3]));
}

// ---------------------------------------------------------------------------
// Kernel 3: scan — parallel. uc (EMA counts), exact numpy-pairwise n via one
// wave's shuffle tree, usage/loss scalars, prefix bases via wave scan.
// ---------------------------------------------------------------------------
__global__ __launch_bounds__(256) void vq_scan(
    const int* __restrict__ cnt, const float* __restrict__ ema_cs,
    const double* __restrict__ loss_acc, float* __restrict__ ucf_ws,
    int* __restrict__ base, int* __restrict__ cursor,
    float* __restrict__ out_uc, float* __restrict__ out_usage,
    float* __restrict__ out_loss)
{
    __shared__ float uc_s[1024];
    __shared__ int   wsum[4];
    __shared__ int   usage_s;
    __shared__ float n_s;
    const int tid  = threadIdx.x;
    const int lane = tid & 63;
    const int wv   = tid >> 6;
    if (tid == 0) usage_s = 0;
    __syncthreads();

    int c4[4];
    int ucount = 0;
#pragma unroll
    for (int j = 0; j < 4; ++j) {
        int k = tid * 4 + j;
        int c = cnt[k];
        c4[j] = c;
        if (c > 0) ucount++;
        uc_s[k] = __fadd_rn(__fmul_rn(ema_cs[k], DECAY_F), __fmul_rn(OMD_F, (float)c));
    }
    atomicAdd(&usage_s, ucount);
    __syncthreads();

    // exact numpy pairwise sum of uc_s[1024]: 8 blocks x 8 accumulators,
    // combined by a commutative-safe xor tree (j bits then b bits).
    if (tid < 64) {
        int b = tid >> 3, j = tid & 7;
        float r = uc_s[b * 128 + j];
#pragma unroll
        for (int i = 1; i < 16; ++i)
            r = __fadd_rn(r, uc_s[b * 128 + 8 * i + j]);
        r = __fadd_rn(r, __shfl_xor(r, 1, 64));
        r = __fadd_rn(r, __shfl_xor(r, 2, 64));
        r = __fadd_rn(r, __shfl_xor(r, 4, 64));
        r = __fadd_rn(r, __shfl_xor(r, 8, 64));
        r = __fadd_rn(r, __shfl_xor(r, 16, 64));
        r = __fadd_rn(r, __shfl_xor(r, 32, 64));
        if (tid == 0) {
            n_s = r;
            *out_usage = __fdiv_rn((float)usage_s, 1024.0f);
            *out_loss  = (float)(*loss_acc / 8388608.0);
        }
    }
    __syncthreads();

    const float n = n_s;
#pragma unroll
    for (int j = 0; j < 4; ++j) {
        int k = tid * 4 + j;
        float ucfv = __fmul_rn(__fdiv_rn(__fadd_rn(uc_s[k], EPS_F), __fadd_rn(n, KEPS_F)), n);
        out_uc[k] = ucfv;
        ucf_ws[k] = ucfv;
    }

    // prefix scan of per-thread count sums -> base/cursor
    int s = c4[0] + c4[1] + c4[2] + c4[3];
    int incl = s;
#pragma unroll
    for (int off = 1; off < 64; off <<= 1) {
        int v = __shfl_up(incl, off, 64);
        if (lane >= off) incl += v;
    }
    if (lane == 63) wsum[wv] = incl;
    __syncthreads();
    int woff = 0;
    for (int w = 0; w < wv; ++w) woff += wsum[w];
    int run = woff + incl - s;
#pragma unroll
    for (int j = 0; j < 4; ++j) {
        int k = tid * 4 + j;
        base[k] = run; cursor[k] = run;
        run += c4[j];
    }
}

// ---------------------------------------------------------------------------
// Kernel 4: scatter row ids + codes into per-code slot lists.
// ---------------------------------------------------------------------------
__global__ __launch_bounds__(256) void vq_scatter(
    const int* __restrict__ idx, int* __restrict__ cursor,
    int* __restrict__ rows, int* __restrict__ codes)
{
    int i = blockIdx.x * 256 + threadIdx.x;
    int k = idx[i];
    int slot = atomicAdd(&cursor[k], 1);
    rows[slot] = i;
    codes[slot] = k;
}

// ---------------------------------------------------------------------------
// Kernel 5: balanced gather — each wave owns a fixed 64-slot chunk of the
// code-sorted slot array (skew-immune). Run-partials accumulated in regs
// (lane = dim), one atomicAdd per run boundary into acc[k][dim].
// ---------------------------------------------------------------------------
__global__ __launch_bounds__(256) void vq_gather(
    const float* __restrict__ x_in, const int* __restrict__ rows,
    const int* __restrict__ codes, float* __restrict__ acc_buf)
{
    const int lane = threadIdx.x & 63;
    const int wv   = threadIdx.x >> 6;
    const int seg  = blockIdx.x * 4 + wv;
    const int g    = seg * 64;

    const int rid = rows[g + lane];    // coalesced
    const int kc  = codes[g + lane];   // coalesced

    float acc = 0.f;
    for (int e8 = 0; e8 < 8; ++e8) {
        float xv[8];
#pragma unroll
        for (int u = 0; u < 8; ++u) {
            int r = __shfl(rid, e8 * 8 + u, 64);
            xv[u] = x_in[(size_t)r * ND + lane];   // independent, pipelined
        }
#pragma unroll
        for (int u = 0; u < 8; ++u) {
            int e = e8 * 8 + u;
            int k = __shfl(kc, e, 64);
            acc = __fadd_rn(acc, xv[u]);
            int knext = __shfl(kc, (e + 1) & 63, 64);
            if (e == 63) knext = -1;
            if (k != knext) {                       // run boundary (uniform)
                atomicAdd(&acc_buf[(size_t)k * ND + lane], acc);
                acc = 0.f;
            }
        }
    }
}

// ---------------------------------------------------------------------------
// Kernel 6: final — upd_ema_w + upd_embeddings from acc.
// ---------------------------------------------------------------------------
__global__ __launch_bounds__(256) void vq_final(
    const float* __restrict__ acc_buf, const float* __restrict__ ema_w,
    const float* __restrict__ ucf, float* __restrict__ out_updw,
    float* __restrict__ out_upde)
{
    int gid = blockIdx.x * 256 + threadIdx.x;
    int k = gid >> 6;
    float w = __fadd_rn(__fmul_rn(ema_w[gid], DECAY_F), __fmul_rn(OMD_F, acc_buf[gid]));
    out_updw[gid] = w;
    out_upde[gid] = __fdiv_rn(w, __fadd_rn(ucf[k], EPS_F));
}

// ---------------------------------------------------------------------------
extern "C" void kernel_launch(void* const* d_in, const int* in_sizes, int n_in,
                              void* d_out, int out_size, void* d_ws, size_t ws_size,
                              hipStream_t stream)
{
    const float* x_in   = (const float*)d_in[0];
    const float* emb    = (const float*)d_in[1];
    const float* ema_cs = (const float*)d_in[2];
    const float* ema_w  = (const float*)d_in[3];

    float* out_qf    = (float*)d_out;                    // [NV*64]
    float* out_enc   = out_qf + (size_t)NV * ND;         // [NV*1024]
    float* out_usage = out_enc + (size_t)NV * NK;        // [1]
    float* out_loss  = out_usage + 1;                    // [1]
    float* out_upde  = out_loss + 1;                     // [1024*64]
    float* out_uc    = out_upde + (size_t)NK * ND;       // [1024]
    float* out_updw  = out_uc + NK;                      // [1024*64]

    char* ws = (char*)d_ws;
    float*  ws_csq    = (float*)(ws);
    int*    ws_cnt    = (int*)(ws + 4096);
    int*    ws_base   = (int*)(ws + 8192);
    int*    ws_cursor = (int*)(ws + 12288);
    float*  ws_ucf    = (float*)(ws + 16384);
    double* ws_loss   = (double*)(ws + 20480);
    int*    ws_idx    = (int*)(ws + 24576);
    int*    ws_rows   = (int*)(ws + 24576 + (size_t)NV * 4);
    int*    ws_codes  = (int*)(ws + 24576 + (size_t)NV * 8);
    float*  ws_acc    = (float*)(ws + 24576 + (size_t)NV * 12);

    vq_prep<<<4, 256, 0, stream>>>(emb, ws_csq, ws_cnt, ws_loss, (float4*)ws_acc);
    vq_assign<<<NV / BR, 256, 0, stream>>>(x_in, emb, ws_csq, out_qf, out_enc,
                                           ws_idx, ws_cnt, ws_loss);
    vq_scan<<<1, 256, 0, stream>>>(ws_cnt, ema_cs, ws_loss, ws_ucf, ws_base,
                                   ws_cursor, out_uc, out_usage, out_loss);
    vq_scatter<<<NV / 256, 256, 0, stream>>>(ws_idx, ws_cursor, ws_rows, ws_codes);
    vq_gather<<<512, 256, 0, stream>>>(x_in, ws_rows, ws_codes, ws_acc);
    vq_final<<<256, 256, 0, stream>>>(ws_acc, ema_w, ws_ucf, out_updw, out_upde);
}

// Round 8
// 299.951 us; speedup vs baseline: 4.4034x; 1.0742x over previous
//
#include <hip/hip_runtime.h>
#include <hip/hip_bf16.h>

#define NK 1024        // codebook size
#define ND 64          // embedding dim
#define NV 131072      // 32*64*64 input vectors
#define BR 128         // rows per assign block
#define DECAY_F 0.99f
#define OMD_F 0.01f
#define EPS_F 1e-5f
#define KEPS_F 0.01024f // fl32(1024 * 1e-5)

typedef const __attribute__((address_space(1))) void* gas1_t;
typedef __attribute__((address_space(3))) void* las3_t;
#define GLOAD_LDS16(gp, lp) \
    __builtin_amdgcn_global_load_lds((gas1_t)(gp), (las3_t)(lp), 16, 0, 0)

// ---- ws layout (bytes) ----
// 0       : csq[1024]    f32
// 4096    : cnt[1024]    i32
// 16384   : ucf[1024]    f32
// 20480   : loss         f64
// 1597440 : acc[65536]   f32 (256 KB)

// ---------------------------------------------------------------------------
// Kernel 1: codebook_sq (numpy pairwise-8 rounding); zero cnt/loss/acc.
// ---------------------------------------------------------------------------
__global__ __launch_bounds__(256) void vq_prep(const float* __restrict__ emb,
                                               float* __restrict__ csq,
                                               int* __restrict__ cnt,
                                               double* loss,
                                               float4* __restrict__ acc4)
{
    int k = blockIdx.x * 256 + threadIdx.x;
    cnt[k] = 0;
    if (k == 0) *loss = 0.0;
    float4 z = make_float4(0.f, 0.f, 0.f, 0.f);
#pragma unroll
    for (int i = 0; i < 16; ++i) acc4[k + i * 1024] = z;   // zero acc[65536]
    float p[ND];
    const float4* e4 = reinterpret_cast<const float4*>(emb + (size_t)k * ND);
#pragma unroll
    for (int i = 0; i < 16; ++i) {
        float4 v = e4[i];
        p[4*i+0] = __fmul_rn(v.x, v.x);
        p[4*i+1] = __fmul_rn(v.y, v.y);
        p[4*i+2] = __fmul_rn(v.z, v.z);
        p[4*i+3] = __fmul_rn(v.w, v.w);
    }
    float r[8];
#pragma unroll
    for (int j = 0; j < 8; ++j) r[j] = p[j];
#pragma unroll
    for (int i = 8; i < ND; i += 8)
#pragma unroll
        for (int j = 0; j < 8; ++j) r[j] = __fadd_rn(r[j], p[i+j]);
    csq[k] = __fadd_rn(__fadd_rn(__fadd_rn(r[0], r[1]), __fadd_rn(r[2], r[3])),
                       __fadd_rn(__fadd_rn(r[4], r[5]), __fadd_rn(r[6], r[7])));
}

// ---------------------------------------------------------------------------
// Kernel 2: register-tiled fp32 GEMM + fused argmin. Distance arithmetic
// byte-identical to round 6. Changes: (a) enc zero-fill moved OUT of the
// tile loop (no per-tile store drains) into the epilogue, interleaved with
// qf/loss per row; one vmcnt(0)+barrier before the 1.0 scatter. (b) direct
// atomicAdd of x into acc[k] per row (replaces scatter+gather kernels).
// ---------------------------------------------------------------------------
__global__ __launch_bounds__(256, 2) void vq_assign(
    const float* __restrict__ x_in, const float* __restrict__ emb,
    const float* __restrict__ csq, float* __restrict__ out_qf,
    float* __restrict__ out_enc, float* __restrict__ acc_buf,
    int* __restrict__ cnt, double* __restrict__ loss_acc)
{
    __shared__ __align__(16) float xs[BR * ND];    // 32 KB, swizzled
    __shared__ __align__(16) float es[128 * ND];   // 32 KB, swizzled
    __shared__ float csq_s[NK];
    __shared__ float isq_s[BR];
    __shared__ double lds_ls[4];

    const int tid  = threadIdx.x;
    const int lane = tid & 63;
    const int wv   = tid >> 6;
    const int tx   = tid & 15;
    const int ty   = tid >> 4;
    const int txs  = tx & 7;
    const int tys  = ty & 7;
    const size_t rowbase = (size_t)blockIdx.x * BR;

    // ---- stage xs + es(tile 0) via async DMA; csq via regular copy ----
#pragma unroll
    for (int c = 0; c < 8; ++c) {
        int f = tid + c * 256;
        int row = f >> 4, ch = f & 15;
        int sch = ch ^ (row & 7);
        GLOAD_LDS16(x_in + rowbase * ND + row * ND + sch * 4, &xs[f * 4]);
    }
#pragma unroll
    for (int c = 0; c < 8; ++c) {
        int f = tid + c * 256;
        int row = f >> 4, ch = f & 15;
        int sch = ch ^ (row & 7);
        GLOAD_LDS16(emb + (size_t)row * ND + sch * 4, &es[f * 4]);
    }
#pragma unroll
    for (int c = 0; c < 4; ++c) csq_s[tid + c * 256] = csq[tid + c * 256];
    __syncthreads();

    // ---- isq per row (numpy pairwise-8 order, swizzled reads) ----
    if (tid < BR) {
        const int rs = tid & 7;
        const float* xr = &xs[tid * ND];
        float r[8];
        {
            float4 a = *(const float4*)&xr[(0 ^ rs) * 4];
            float4 b = *(const float4*)&xr[(1 ^ rs) * 4];
            r[0] = __fmul_rn(a.x, a.x); r[1] = __fmul_rn(a.y, a.y);
            r[2] = __fmul_rn(a.z, a.z); r[3] = __fmul_rn(a.w, a.w);
            r[4] = __fmul_rn(b.x, b.x); r[5] = __fmul_rn(b.y, b.y);
            r[6] = __fmul_rn(b.z, b.z); r[7] = __fmul_rn(b.w, b.w);
        }
#pragma unroll
        for (int g = 1; g < 8; ++g) {
            float4 a = *(const float4*)&xr[((2*g)   ^ rs) * 4];
            float4 b = *(const float4*)&xr[((2*g+1) ^ rs) * 4];
            r[0] = __fadd_rn(r[0], __fmul_rn(a.x, a.x));
            r[1] = __fadd_rn(r[1], __fmul_rn(a.y, a.y));
            r[2] = __fadd_rn(r[2], __fmul_rn(a.z, a.z));
            r[3] = __fadd_rn(r[3], __fmul_rn(a.w, a.w));
            r[4] = __fadd_rn(r[4], __fmul_rn(b.x, b.x));
            r[5] = __fadd_rn(r[5], __fmul_rn(b.y, b.y));
            r[6] = __fadd_rn(r[6], __fmul_rn(b.z, b.z));
            r[7] = __fadd_rn(r[7], __fmul_rn(b.w, b.w));
        }
        isq_s[tid] = __fadd_rn(__fadd_rn(__fadd_rn(r[0], r[1]), __fadd_rn(r[2], r[3])),
                               __fadd_rn(__fadd_rn(r[4], r[5]), __fadd_rn(r[6], r[7])));
    }

    float best[8];
    int   bestk[8];
#pragma unroll
    for (int i = 0; i < 8; ++i) { best[i] = 3.4e38f; bestk[i] = 0; }

    for (int t = 0; t < 8; ++t) {
        float acc[8][8];
#pragma unroll
        for (int i = 0; i < 8; ++i)
#pragma unroll
            for (int j = 0; j < 8; ++j) acc[i][j] = 0.f;

        for (int ch = 0; ch < 16; ++ch) {
            const int xo = (ch ^ tys) * 4;
            const int eo = (ch ^ txs) * 4;
            float4 xf[8], ef[8];
#pragma unroll
            for (int i = 0; i < 8; ++i)
                xf[i] = *(const float4*)&xs[(ty + 16*i) * ND + xo];
#pragma unroll
            for (int j = 0; j < 8; ++j)
                ef[j] = *(const float4*)&es[(tx + 16*j) * ND + eo];
#pragma unroll
            for (int i = 0; i < 8; ++i) {
#pragma unroll
                for (int j = 0; j < 8; ++j) {
                    float a = acc[i][j];
                    a = __builtin_fmaf(xf[i].x, ef[j].x, a);
                    a = __builtin_fmaf(xf[i].y, ef[j].y, a);
                    a = __builtin_fmaf(xf[i].z, ef[j].z, a);
                    a = __builtin_fmaf(xf[i].w, ef[j].w, a);
                    acc[i][j] = a;
                }
            }
        }

        // compare (codes ascend with j and t -> strict < keeps first index)
#pragma unroll
        for (int i = 0; i < 8; ++i) {
            float isq = isq_s[ty + 16*i];
#pragma unroll
            for (int j = 0; j < 8; ++j) {
                float dist = __fsub_rn(__fadd_rn(isq, csq_s[t * 128 + tx + 16*j]),
                                       __fmul_rn(2.0f, acc[i][j]));
                if (dist < best[i]) { best[i] = dist; bestk[i] = t * 128 + tx + 16*j; }
            }
        }

        __syncthreads();            // all waves done reading es tile t
        if (t < 7) {
#pragma unroll
            for (int c = 0; c < 8; ++c) {
                int f = tid + c * 256;
                int row = f >> 4, ch = f & 15;
                int sch = ch ^ (row & 7);
                GLOAD_LDS16(emb + (size_t)(t + 1) * 128 * ND + row * ND + sch * 4,
                            &es[f * 4]);
            }
        }
        __syncthreads();            // DMA drained: tile t+1 present
    }

    // ---- cross-thread argmin reduction (overlay scratch on es) ----
    float* red_d = es;
    int*   red_i = reinterpret_cast<int*>(es + 2048);
#pragma unroll
    for (int i = 0; i < 8; ++i) {
        red_d[(ty + 16*i) * 16 + tx] = best[i];
        red_i[(ty + 16*i) * 16 + tx] = bestk[i];
    }
    __syncthreads();
    if (tid < BR) {
        float bd = red_d[tid * 16];
        int   bk = red_i[tid * 16];
#pragma unroll
        for (int c = 1; c < 16; ++c) {
            float d  = red_d[tid * 16 + c];
            int   k2 = red_i[tid * 16 + c];
            if (d < bd || (d == bd && k2 < bk)) { bd = d; bk = k2; }
        }
        atomicAdd(&cnt[bk], 1);
        red_i[tid * 16] = bk;             // publish for epilogue
    }
    __syncthreads();

    // ---- epilogue: enc zero-fill + quantized_flow + loss + acc atomics,
    //      interleaved per row so stores drain under compute ----
    float lsum = 0.f;
    const int lsw = (lane >> 2);        // chunk of element `lane`
    const float4 zv = make_float4(0.f, 0.f, 0.f, 0.f);
    for (int r = 0; r < 32; ++r) {
        int rl = wv * 32 + r;
        int kr = red_i[rl * 16];
        size_t grow = rowbase + rl;
        // zero this row's encodings (4 coalesced 1KB stores, no wait)
        float4* dst = reinterpret_cast<float4*>(out_enc + grow * NK);
#pragma unroll
        for (int jj = 0; jj < 4; ++jj) dst[jj * 64 + lane] = zv;
        float xv = xs[rl * ND + ((lsw ^ (rl & 7)) << 2) + (lane & 3)];
        float ev = emb[(size_t)kr * ND + lane];
        out_qf[grow * ND + lane] = __fadd_rn(xv, __fsub_rn(ev, xv));
        float dd = __fsub_rn(xv, ev);
        lsum = __builtin_fmaf(dd, dd, lsum);
        atomicAdd(&acc_buf[(size_t)kr * ND + lane], xv);   // segment sum
    }
    double ls = (double)lsum;
#pragma unroll
    for (int off = 32; off >= 1; off >>= 1) ls += __shfl_xor(ls, off, 64);
    if (lane == 0) lds_ls[wv] = ls;

    // single drain: all zero-stores complete before the 1.0 scatter
    asm volatile("s_waitcnt vmcnt(0)" ::: "memory");
    __syncthreads();

    if (tid < BR) {
        int bk = red_i[tid * 16];
        out_enc[(rowbase + tid) * NK + bk] = 1.0f;
    }
    if (tid == 0)
        atomicAdd(loss_acc, (lds_ls[0] + lds_ls[1]) + (lds_ls[2] + lds_ls[3]));
}

// ---------------------------------------------------------------------------
// Kernel 3: scan — uc (EMA counts), exact numpy-pairwise n via one wave's
// shuffle tree, usage/loss scalars, ucf.
// ---------------------------------------------------------------------------
__global__ __launch_bounds__(256) void vq_scan(
    const int* __restrict__ cnt, const float* __restrict__ ema_cs,
    const double* __restrict__ loss_acc, float* __restrict__ ucf_ws,
    float* __restrict__ out_uc, float* __restrict__ out_usage,
    float* __restrict__ out_loss)
{
    __shared__ float uc_s[1024];
    __shared__ int   usage_s;
    __shared__ float n_s;
    const int tid  = threadIdx.x;
    if (tid == 0) usage_s = 0;
    __syncthreads();

    int ucount = 0;
#pragma unroll
    for (int j = 0; j < 4; ++j) {
        int k = tid * 4 + j;
        int c = cnt[k];
        if (c > 0) ucount++;
        uc_s[k] = __fadd_rn(__fmul_rn(ema_cs[k], DECAY_F), __fmul_rn(OMD_F, (float)c));
    }
    atomicAdd(&usage_s, ucount);
    __syncthreads();

    // exact numpy pairwise sum of uc_s[1024]: 8 blocks x 8 accumulators,
    // combined by a commutative-safe xor tree (j bits then b bits).
    if (tid < 64) {
        int b = tid >> 3, j = tid & 7;
        float r = uc_s[b * 128 + j];
#pragma unroll
        for (int i = 1; i < 16; ++i)
            r = __fadd_rn(r, uc_s[b * 128 + 8 * i + j]);
        r = __fadd_rn(r, __shfl_xor(r, 1, 64));
        r = __fadd_rn(r, __shfl_xor(r, 2, 64));
        r = __fadd_rn(r, __shfl_xor(r, 4, 64));
        r = __fadd_rn(r, __shfl_xor(r, 8, 64));
        r = __fadd_rn(r, __shfl_xor(r, 16, 64));
        r = __fadd_rn(r, __shfl_xor(r, 32, 64));
        if (tid == 0) {
            n_s = r;
            *out_usage = __fdiv_rn((float)usage_s, 1024.0f);
            *out_loss  = (float)(*loss_acc / 8388608.0);
        }
    }
    __syncthreads();

    const float n = n_s;
#pragma unroll
    for (int j = 0; j < 4; ++j) {
        int k = tid * 4 + j;
        float ucfv = __fmul_rn(__fdiv_rn(__fadd_rn(uc_s[k], EPS_F), __fadd_rn(n, KEPS_F)), n);
        out_uc[k] = ucfv;
        ucf_ws[k] = ucfv;
    }
}

// ---------------------------------------------------------------------------
// Kernel 4: final — upd_ema_w + upd_embeddings from acc.
// ---------------------------------------------------------------------------
__global__ __launch_bounds__(256) void vq_final(
    const float* __restrict__ acc_buf, const float* __restrict__ ema_w,
    const float* __restrict__ ucf, float* __restrict__ out_updw,
    float* __restrict__ out_upde)
{
    int gid = blockIdx.x * 256 + threadIdx.x;
    int k = gid >> 6;
    float w = __fadd_rn(__fmul_rn(ema_w[gid], DECAY_F), __fmul_rn(OMD_F, acc_buf[gid]));
    out_updw[gid] = w;
    out_upde[gid] = __fdiv_rn(w, __fadd_rn(ucf[k], EPS_F));
}

// ---------------------------------------------------------------------------
extern "C" void kernel_launch(void* const* d_in, const int* in_sizes, int n_in,
                              void* d_out, int out_size, void* d_ws, size_t ws_size,
                              hipStream_t stream)
{
    const float* x_in   = (const float*)d_in[0];
    const float* emb    = (const float*)d_in[1];
    const float* ema_cs = (const float*)d_in[2];
    const float* ema_w  = (const float*)d_in[3];

    float* out_qf    = (float*)d_out;                    // [NV*64]
    float* out_enc   = out_qf + (size_t)NV * ND;         // [NV*1024]
    float* out_usage = out_enc + (size_t)NV * NK;        // [1]
    float* out_loss  = out_usage + 1;                    // [1]
    float* out_upde  = out_loss + 1;                     // [1024*64]
    float* out_uc    = out_upde + (size_t)NK * ND;       // [1024]
    float* out_updw  = out_uc + NK;                      // [1024*64]

    char* ws = (char*)d_ws;
    float*  ws_csq    = (float*)(ws);
    int*    ws_cnt    = (int*)(ws + 4096);
    float*  ws_ucf    = (float*)(ws + 16384);
    double* ws_loss   = (double*)(ws + 20480);
    float*  ws_acc    = (float*)(ws + 1597440);

    vq_prep<<<4, 256, 0, stream>>>(emb, ws_csq, ws_cnt, ws_loss, (float4*)ws_acc);
    vq_assign<<<NV / BR, 256, 0, stream>>>(x_in, emb, ws_csq, out_qf, out_enc,
                                           ws_acc, ws_cnt, ws_loss);
    vq_scan<<<1, 256, 0, stream>>>(ws_cnt, ema_cs, ws_loss, ws_ucf,
                                   out_uc, out_usage, out_loss);
    vq_final<<<256, 256, 0, stream>>>(ws_acc, ema_w, ws_ucf, out_updw, out_upde);
}